// Round 8
// baseline (80.286 us; speedup 1.0000x reference)
//
#include <hip/hip_runtime.h>
#include <cmath>

#define IMG_H 512
#define IMG_W 512
#define TILE_X 64
#define TILE_Y 32
#define LH 42              // TILE_Y + 10 halo rows
#define SW 80              // staged row width in floats (16B-aligned windows)
#define SPLANE (LH * SW)   // 3360 floats per input
#define NCHUNK (2 * LH * 20)   // 1680 float4 chunks total (both inputs)
#define NBLOCKS (8 * 16 * 32)
#define NPIX (8 * 4 * 512 * 512)

struct Weights { float w[11]; };

// Round-to-nearest-even f32 -> bf16
static __device__ __forceinline__ unsigned bf16_rne(float x) {
    unsigned u = __float_as_uint(x);
    u += 0x7FFFu + ((u >> 16) & 1u);
    return u >> 16;
}
static __device__ __forceinline__ unsigned pack_bf16x2(float a, float b) {
    return bf16_rne(a) | (bf16_rne(b) << 16);
}

// Load one float4 chunk of the staging region. Chunk s: input = s>=840,
// row = idx/20, col4 = (idx%20)*4. Global window cols [x0-8, x0+72).
// Addresses are clamped (always in-bounds); OOB elements zeroed when edge.
static __device__ __forceinline__ float4 stage_load(int s,
        const float* __restrict__ P, const float* __restrict__ T,
        int x0, int y0, bool edge) {
    int idx = s;
    const float* base = P;
    if (s >= SPLANE / 4) { idx = s - SPLANE / 4; base = T; }
    int row = idx / 20;
    int c4  = (idx - row * 20) * 4;
    int gy  = y0 + row - 5;
    int gx0 = x0 + c4 - 8;
    int cy  = min(max(gy, 0), IMG_H - 1);
    int cx  = min(max(gx0, 0), IMG_W - 4);
    float4 v = *(const float4*)(base + cy * IMG_W + cx);
    if (edge) {
        bool oky = ((unsigned)gy < IMG_H);
        v.x = (oky && (unsigned)(gx0 + 0) < IMG_W) ? v.x : 0.f;
        v.y = (oky && (unsigned)(gx0 + 1) < IMG_W) ? v.y : 0.f;
        v.z = (oky && (unsigned)(gx0 + 2) < IMG_W) ? v.z : 0.f;
        v.w = (oky && (unsigned)(gx0 + 3) < IMG_W) ? v.w : 0.f;
    }
    return v;
}

// LDS: sraw 26.9KB + hAB 21KB + hC 10.5KB = 57.8KB -> 2 blocks/CU.
// Staging batches 3-4 independent dwordx4 per thread (one pipelined vmcnt wait)
// and pre-zeroes OOB, so Phase B is guard-free and reads only LDS.
__global__ __launch_bounds__(512, 4)
void ssim_tile_kernel(const float* __restrict__ pred,
                      const float* __restrict__ targ,
                      float* __restrict__ partials,
                      Weights wt)
{
    __shared__ float sraw[2 * SPLANE];   // raw p tile, then raw t tile (f32)
    __shared__ uint2 hAB[LH * TILE_X];   // .x=(h1,h2) bf16x2, .y=(h11,h22) bf16x2
    __shared__ float hC[LH * TILE_X];    // conv(pt) kept f32 (sigma12 delicate)
    __shared__ float wsum[8];

    const int tid = threadIdx.x;
    const int x0 = blockIdx.x * TILE_X;
    const int y0 = blockIdx.y * TILE_Y;
    const int plane = blockIdx.z;
    const float* __restrict__ P = pred + (size_t)plane * IMG_H * IMG_W;
    const float* __restrict__ T = targ + (size_t)plane * IMG_H * IMG_W;
    const bool edge = (blockIdx.x == 0) | (blockIdx.x == gridDim.x - 1) |
                      (blockIdx.y == 0) | (blockIdx.y == gridDim.y - 1);

    // ---- Phase A: batched staging, all loads in flight before any LDS write ----
    {
        int s0 = tid, s1 = tid + 512, s2 = tid + 1024, s3 = tid + 1536;
        bool has3 = (s3 < NCHUNK);     // tid < 144
        int s3c = has3 ? s3 : (NCHUNK - 1);
        float4 v0 = stage_load(s0, P, T, x0, y0, edge);
        float4 v1 = stage_load(s1, P, T, x0, y0, edge);
        float4 v2 = stage_load(s2, P, T, x0, y0, edge);
        float4 v3 = stage_load(s3c, P, T, x0, y0, edge);
        *(float4*)&sraw[s0 * 4] = v0;
        *(float4*)&sraw[s1 * 4] = v1;
        *(float4*)&sraw[s2 * 4] = v2;
        if (has3) *(float4*)&sraw[s3 * 4] = v3;
    }
    __syncthreads();

    // ---- Phase B: horizontal 11-tap pass from LDS (guard-free) ----
    // 42 rows x 16 col-groups (4 outputs each) = 672 work items.
    for (int i = tid; i < LH * 16; i += 512) {
        int r = i >> 4;
        int c4 = (i & 15) * 4;
        const float* rp = &sraw[r * SW + c4];
        const float* rt = &sraw[SPLANE + r * SW + c4];
        float p[20], t[20];
        #pragma unroll
        for (int q = 0; q < 5; ++q) {
            *(float4*)&p[q * 4] = *(const float4*)&rp[q * 4];
            *(float4*)&t[q * 4] = *(const float4*)&rt[q * 4];
        }
        float s1[4], s2[4], s11[4], s22[4], s12[4];
        #pragma unroll
        for (int o = 0; o < 4; ++o) { s1[o]=0.f; s2[o]=0.f; s11[o]=0.f; s22[o]=0.f; s12[o]=0.f; }
        #pragma unroll
        for (int k = 0; k < 11; ++k) {
            float w = wt.w[k];
            #pragma unroll
            for (int o = 0; o < 4; ++o) {
                float pv = p[o + 3 + k], tv = t[o + 3 + k];
                float wp = w * pv, wtv = w * tv;
                s1[o]  += wp;
                s2[o]  += wtv;
                s11[o] += wp * pv;
                s22[o] += wtv * tv;
                s12[o] += wp * tv;
            }
        }
        int ho = r * TILE_X + c4;
        #pragma unroll
        for (int o = 0; o < 4; ++o)
            hAB[ho + o] = make_uint2(pack_bf16x2(s1[o],  s2[o]),
                                     pack_bf16x2(s11[o], s22[o]));
        *(float4*)&hC[ho] = make_float4(s12[0], s12[1], s12[2], s12[3]);
    }
    __syncthreads();

    // ---- Phase C: vertical 11-tap pass + SSIM, f32 compute, 4 rows/thread ----
    const int c  = tid & 63;          // output column (conflict-free)
    const int r0 = (tid >> 6) * 4;    // 8 row-groups x 4 rows = 32 rows exactly
    float a1[4], a2[4], a11[4], a22[4], a12[4];
    #pragma unroll
    for (int o = 0; o < 4; ++o) { a1[o]=0.f; a2[o]=0.f; a11[o]=0.f; a22[o]=0.f; a12[o]=0.f; }

    #pragma unroll
    for (int j = 0; j < 14; ++j) {     // h rows r0 .. r0+13 cover outputs r0..r0+3
        int hr = (r0 + j) * TILE_X + c;
        uint2 uab = hAB[hr];           // ds_read_b64, conflict-free
        float v12  = hC[hr];
        float v1  = __uint_as_float(uab.x << 16);          // bf16 -> f32 = shift
        float v2  = __uint_as_float(uab.x & 0xFFFF0000u);
        float v11 = __uint_as_float(uab.y << 16);
        float v22 = __uint_as_float(uab.y & 0xFFFF0000u);
        #pragma unroll
        for (int o = 0; o < 4; ++o) {
            int k = j - o;
            if (k >= 0 && k < 11) {    // compile-time resolved
                float w = wt.w[k];
                a1[o]  += w * v1;
                a2[o]  += w * v2;
                a11[o] += w * v11;
                a22[o] += w * v22;
                a12[o] += w * v12;
            }
        }
    }

    float lsum = 0.f;
    #pragma unroll
    for (int o = 0; o < 4; ++o) {
        float mu1 = a1[o], mu2 = a2[o];
        float m11 = mu1 * mu1, m22 = mu2 * mu2, m12 = mu1 * mu2;
        float sg1 = a11[o] - m11;
        float sg2 = a22[o] - m22;
        float sg12 = a12[o] - m12;
        float num = (2.f * m12 + 1e-4f) * (2.f * sg12 + 9e-4f);
        float den = (m11 + m22 + 1e-4f) * (sg1 + sg2 + 9e-4f);
        lsum += __fdividef(num, den);
    }

    // ---- Block reduction (deterministic) ----
    #pragma unroll
    for (int off = 32; off > 0; off >>= 1) lsum += __shfl_down(lsum, off);
    if ((tid & 63) == 0) wsum[tid >> 6] = lsum;
    __syncthreads();
    if (tid == 0) {
        float bsum = 0.f;
        #pragma unroll
        for (int wv = 0; wv < 8; ++wv) bsum += wsum[wv];
        partials[(blockIdx.z * gridDim.y + blockIdx.y) * gridDim.x + blockIdx.x] = bsum;
    }
}

__global__ void ssim_finalize(const float* __restrict__ partials, float* __restrict__ out)
{
    __shared__ double red[256];
    double s = 0.0;
    for (int i = threadIdx.x; i < NBLOCKS; i += 256) s += (double)partials[i];
    red[threadIdx.x] = s;
    __syncthreads();
    for (int stride = 128; stride > 0; stride >>= 1) {
        if ((int)threadIdx.x < stride) red[threadIdx.x] += red[threadIdx.x + stride];
        __syncthreads();
    }
    if (threadIdx.x == 0) out[0] = (float)(1.0 - red[0] / (double)NPIX);
}

extern "C" void kernel_launch(void* const* d_in, const int* in_sizes, int n_in,
                              void* d_out, int out_size, void* d_ws, size_t ws_size,
                              hipStream_t stream) {
    const float* pred = (const float*)d_in[0];
    const float* targ = (const float*)d_in[1];
    float* out = (float*)d_out;
    float* partials = (float*)d_ws;   // 4096 floats, every slot written each call

    Weights wt;
    {
        float g[11];
        float s = 0.f;
        for (int i = 0; i < 11; ++i) {
            float d = (float)(i - 5);
            g[i] = expf(-d * d / (2.f * 1.5f * 1.5f));
            s += g[i];
        }
        for (int i = 0; i < 11; ++i) wt.w[i] = g[i] / s;
    }

    dim3 grid(IMG_W / TILE_X, IMG_H / TILE_Y, 32);   // (8, 16, 32) = 4096 blocks
    ssim_tile_kernel<<<grid, 512, 0, stream>>>(pred, targ, partials, wt);
    ssim_finalize<<<1, 256, 0, stream>>>(partials, out);
}

// Round 9
// 77.346 us; speedup vs baseline: 1.0380x; 1.0380x over previous
//
#include <hip/hip_runtime.h>
#include <cmath>

#define IMG_H 512
#define IMG_W 512
#define TILE_X 64
#define TILE_Y 54          // output rows per block (last y-block partially masked)
#define LH 64              // TILE_Y + 10 halo rows; 64*16 = 1024 items = 2 uniform rounds
#define GRID_Y 10          // ceil(512/54)
#define NBLOCKS (8 * GRID_Y * 32)
#define NPIX (8 * 4 * 512 * 512)

struct Weights { float w[11]; };

// Round-to-nearest-even f32 -> bf16
static __device__ __forceinline__ unsigned bf16_rne(float x) {
    unsigned u = __float_as_uint(x);
    u += 0x7FFFu + ((u >> 16) & 1u);
    return u >> 16;
}
static __device__ __forceinline__ unsigned pack_bf16x2(float a, float b) {
    return bf16_rne(a) | (bf16_rne(b) << 16);
}

// LDS: hAB 64x64 uint2 = 32.8KB + hC 64x64 f32 = 16.4KB = 49.2KB -> 3 blocks/CU
// (24 waves/CU) provided VGPR <= 64 (bound (512,4) caps at 64; Phase B loop kept
// unroll-1 so only one 20-float window is live).
__global__ __launch_bounds__(512, 4)
void ssim_tile_kernel(const float* __restrict__ pred,
                      const float* __restrict__ targ,
                      float* __restrict__ partials,
                      Weights wt)
{
    __shared__ uint2 hAB[LH * TILE_X];   // .x=(h1,h2) bf16x2, .y=(h11,h22) bf16x2
    __shared__ float hC[LH * TILE_X];    // conv(pt) kept f32 (sigma12 delicate)
    __shared__ float wsum[8];

    const int tid = threadIdx.x;
    const int x0 = blockIdx.x * TILE_X;
    const int y0 = blockIdx.y * TILE_Y;
    const int plane = blockIdx.z;
    const float* __restrict__ P = pred + (size_t)plane * IMG_H * IMG_W;
    const float* __restrict__ T = targ + (size_t)plane * IMG_H * IMG_W;

    // ---- Phase B: horizontal 11-tap pass directly from global memory ----
    // 64 rows x 16 col-groups (4 outputs each) = 1024 items: exactly 2 per thread.
    #pragma unroll 1
    for (int rep = 0; rep < 2; ++rep) {
        int i = tid + rep * 512;
        int r = i >> 4;
        int c4 = (i & 15) * 4;
        int gy = y0 + r - 5;
        float p[20], t[20];
        if ((unsigned)gy < IMG_H) {
            const float* rp = P + gy * IMG_W;
            const float* rt = T + gy * IMG_W;
            int gx0 = x0 + c4 - 8;                 // 16B aligned
            if (gx0 >= 0 && gx0 + 20 <= IMG_W) {   // interior fast path
                #pragma unroll
                for (int q = 0; q < 5; ++q) {
                    *(float4*)&p[q * 4] = *(const float4*)&rp[gx0 + q * 4];
                    *(float4*)&t[q * 4] = *(const float4*)&rt[gx0 + q * 4];
                }
            } else {                               // image x-edge: guarded scalar
                #pragma unroll
                for (int q = 0; q < 20; ++q) {
                    int gx = gx0 + q;
                    bool v = (unsigned)gx < IMG_W;
                    p[q] = v ? rp[gx] : 0.f;
                    t[q] = v ? rt[gx] : 0.f;
                }
            }
        } else {
            #pragma unroll
            for (int q = 0; q < 20; ++q) { p[q] = 0.f; t[q] = 0.f; }
        }

        float s1[4], s2[4], s11[4], s22[4], s12[4];
        #pragma unroll
        for (int o = 0; o < 4; ++o) { s1[o]=0.f; s2[o]=0.f; s11[o]=0.f; s22[o]=0.f; s12[o]=0.f; }
        #pragma unroll
        for (int k = 0; k < 11; ++k) {
            float w = wt.w[k];
            #pragma unroll
            for (int o = 0; o < 4; ++o) {
                float pv = p[o + 3 + k], tv = t[o + 3 + k];
                float wp = w * pv, wtv = w * tv;
                s1[o]  += wp;
                s2[o]  += wtv;
                s11[o] += wp * pv;
                s22[o] += wtv * tv;
                s12[o] += wp * tv;
            }
        }
        int ho = r * TILE_X + c4;
        #pragma unroll
        for (int o = 0; o < 4; ++o)
            hAB[ho + o] = make_uint2(pack_bf16x2(s1[o],  s2[o]),
                                     pack_bf16x2(s11[o], s22[o]));
        *(float4*)&hC[ho] = make_float4(s12[0], s12[1], s12[2], s12[3]);
    }
    __syncthreads();

    // ---- Phase C: vertical 11-tap pass + SSIM, 7 rows/thread (rows 54/55 masked) ----
    const int c  = tid & 63;          // output column (conflict-free)
    const int r0 = (tid >> 6) * 7;    // 8 groups x 7 rows = 56 >= 54
    float a1[7], a2[7], a11[7], a22[7], a12[7];
    #pragma unroll
    for (int o = 0; o < 7; ++o) { a1[o]=0.f; a2[o]=0.f; a11[o]=0.f; a22[o]=0.f; a12[o]=0.f; }

    #pragma unroll
    for (int j = 0; j < 17; ++j) {     // h rows r0 .. r0+16 cover outputs r0..r0+6
        int hrr = r0 + j;
        hrr = hrr > (LH - 1) ? (LH - 1) : hrr;   // clamp (only masked rows affected)
        int hr = hrr * TILE_X + c;
        uint2 uab = hAB[hr];           // ds_read_b64, conflict-free
        float v12  = hC[hr];
        float v1  = __uint_as_float(uab.x << 16);          // bf16 -> f32 = shift
        float v2  = __uint_as_float(uab.x & 0xFFFF0000u);
        float v11 = __uint_as_float(uab.y << 16);
        float v22 = __uint_as_float(uab.y & 0xFFFF0000u);
        #pragma unroll
        for (int o = 0; o < 7; ++o) {
            int k = j - o;
            if (k >= 0 && k < 11) {    // compile-time resolved
                float w = wt.w[k];
                a1[o]  += w * v1;
                a2[o]  += w * v2;
                a11[o] += w * v11;
                a22[o] += w * v22;
                a12[o] += w * v12;
            }
        }
    }

    float lsum = 0.f;
    #pragma unroll
    for (int o = 0; o < 7; ++o) {
        int rr = r0 + o;
        bool valid = (rr < TILE_Y) && (y0 + rr < IMG_H);
        float mu1 = a1[o], mu2 = a2[o];
        float m11 = mu1 * mu1, m22 = mu2 * mu2, m12 = mu1 * mu2;
        float sg1 = a11[o] - m11;
        float sg2 = a22[o] - m22;
        float sg12 = a12[o] - m12;
        float num = (2.f * m12 + 1e-4f) * (2.f * sg12 + 9e-4f);
        float den = (m11 + m22 + 1e-4f) * (sg1 + sg2 + 9e-4f);
        float v = __fdividef(num, den);
        lsum += valid ? v : 0.f;       // select (NaN-safe), not multiply
    }

    // ---- Block reduction (deterministic) ----
    #pragma unroll
    for (int off = 32; off > 0; off >>= 1) lsum += __shfl_down(lsum, off);
    if ((tid & 63) == 0) wsum[tid >> 6] = lsum;
    __syncthreads();
    if (tid == 0) {
        float bsum = 0.f;
        #pragma unroll
        for (int wv = 0; wv < 8; ++wv) bsum += wsum[wv];
        partials[(blockIdx.z * gridDim.y + blockIdx.y) * gridDim.x + blockIdx.x] = bsum;
    }
}

__global__ void ssim_finalize(const float* __restrict__ partials, float* __restrict__ out)
{
    __shared__ double red[256];
    double s = 0.0;
    for (int i = threadIdx.x; i < NBLOCKS; i += 256) s += (double)partials[i];
    red[threadIdx.x] = s;
    __syncthreads();
    for (int stride = 128; stride > 0; stride >>= 1) {
        if ((int)threadIdx.x < stride) red[threadIdx.x] += red[threadIdx.x + stride];
        __syncthreads();
    }
    if (threadIdx.x == 0) out[0] = (float)(1.0 - red[0] / (double)NPIX);
}

extern "C" void kernel_launch(void* const* d_in, const int* in_sizes, int n_in,
                              void* d_out, int out_size, void* d_ws, size_t ws_size,
                              hipStream_t stream) {
    const float* pred = (const float*)d_in[0];
    const float* targ = (const float*)d_in[1];
    float* out = (float*)d_out;
    float* partials = (float*)d_ws;   // 2560 floats, every slot written each call

    Weights wt;
    {
        float g[11];
        float s = 0.f;
        for (int i = 0; i < 11; ++i) {
            float d = (float)(i - 5);
            g[i] = expf(-d * d / (2.f * 1.5f * 1.5f));
            s += g[i];
        }
        for (int i = 0; i < 11; ++i) wt.w[i] = g[i] / s;
    }

    dim3 grid(IMG_W / TILE_X, GRID_Y, 32);   // (8, 10, 32) = 2560 blocks
    ssim_tile_kernel<<<grid, 512, 0, stream>>>(pred, targ, partials, wt);
    ssim_finalize<<<1, 256, 0, stream>>>(partials, out);
}